// Round 9
// baseline (448.463 us; speedup 1.0000x reference)
//
#include <hip/hip_runtime.h>
#include <math.h>

#define EMBED 1024
#define HEADS 16
#define HDIM  64
#define HIDDEN 4096
#define BATCH 2
#define SEQ   2048
#define TOK   (BATCH * SEQ)   // 4096 tokens

typedef _Float16 f16;
typedef f16 f16x8 __attribute__((ext_vector_type(8)));
typedef f16 f16x4 __attribute__((ext_vector_type(4)));
typedef float f32x4 __attribute__((ext_vector_type(4)));
typedef float f32x16 __attribute__((ext_vector_type(16)));

// async global->LDS, 16B per lane. LDS dest = wave-uniform base + lane*16.
__device__ __forceinline__ void gload16(const void* g, void* s) {
  __builtin_amdgcn_global_load_lds(
      (const __attribute__((address_space(1))) unsigned int*)g,
      (__attribute__((address_space(3))) unsigned int*)s, 16, 0, 0);
}

// ---------------------------------------------------------------------------
// fp16 MFMA GEMM, counted-vmcnt pipelined (T4): C = act((A @ W + bias)*scale)
// A f16 [M][K]; Wt f16 [N][K]. 128x128 tile, BK=32, 4 waves, 4x4 frags of
// 16x16x32. Double-buffered LDS; raw s_barrier + s_waitcnt vmcnt(4) so the
// next-next tile's global_load_lds stay in flight across barriers (never
// drain to 0 in the loop). SPLITK>1 writes raw f32 partials (bias in add_ln).
template<int RELU, int OUT16, int QKV, int SPLITK>
__global__ __launch_bounds__(256, 3)
void gemm_f16(const f16* __restrict__ A, const f16* __restrict__ Wt,
              const float* __restrict__ bias0, const float* __restrict__ bias1,
              const float* __restrict__ bias2, void* __restrict__ Cv,
              int N, int K, int nbx) {
  __shared__ f16 As[2][512 * 8];
  __shared__ f16 Bs[2][512 * 8];
  const int tid = threadIdx.x;
  const int l = tid & 63, w = tid >> 6;
  const int g = l >> 4, ln = l & 15;
  int bid = blockIdx.x;
  int slice = 0;
  if (SPLITK > 1) { slice = bid % SPLITK; bid /= SPLITK; }
  const int ntiles = gridDim.x / SPLITK;
  const int cpx = ntiles >> 3;
  bid = (bid & 7) * cpx + (bid >> 3);     // XCD swizzle over tiles
  const int m0 = (bid / nbx) << 7;
  const int n0 = (bid % nbx) << 7;
  const int wr = w >> 1, wc = w & 1;
  const int ksl = K / SPLITK;
  const int kbeg = slice * ksl, kend = kbeg + ksl;

  f32x4 acc[4][4] = {};

  auto stage = [&](int buf, int k0) {
#pragma unroll
    for (int p = 0; p < 2; ++p) {
      const int u0 = p * 256 + w * 64;
      const int ks = u0 >> 7;
      const int row = ((u0 + l) & 127) ^ ks;
      gload16(A + (size_t)(m0 + row) * K + k0 + ks * 8, (void*)&As[buf][u0 * 8]);
    }
#pragma unroll
    for (int p = 0; p < 2; ++p) {
      const int u0 = p * 256 + w * 64;
      const int ks = u0 >> 7;
      const int col = ((u0 + l) & 127) ^ ks;
      gload16(Wt + (size_t)(n0 + col) * K + k0 + ks * 8, (void*)&Bs[buf][u0 * 8]);
    }
  };

  // prologue: two tiles in flight; wait only for the first (vmcnt 8 -> 4)
  stage(0, kbeg);
  stage(1, kbeg + 32);
  asm volatile("s_waitcnt vmcnt(4)" ::: "memory");
  __builtin_amdgcn_s_barrier();

  int cur = 0;
#pragma unroll 1
  for (int k0 = kbeg; k0 < kend; k0 += 32) {
    f16x8 af[4], bf[4];
#pragma unroll
    for (int m = 0; m < 4; ++m)
      af[m] = *(const f16x8*)&As[cur][(g * 128 + ((wr * 64 + m * 16 + ln) ^ g)) * 8];
#pragma unroll
    for (int n = 0; n < 4; ++n)
      bf[n] = *(const f16x8*)&Bs[cur][(g * 128 + ((wc * 64 + n * 16 + ln) ^ g)) * 8];
    asm volatile("s_waitcnt lgkmcnt(0)" ::: "memory");   // frags in regs
    __builtin_amdgcn_sched_barrier(0);
    __builtin_amdgcn_s_barrier();                        // all waves done reading cur
    const bool morestage = (k0 + 64 < kend);
    if (morestage) stage(cur, k0 + 64);                  // overwrite cur for k+2
    __builtin_amdgcn_s_setprio(1);
#pragma unroll
    for (int m = 0; m < 4; ++m)
#pragma unroll
      for (int n = 0; n < 4; ++n)
        acc[m][n] = __builtin_amdgcn_mfma_f32_16x16x32_f16(af[m], bf[n], acc[m][n], 0, 0, 0);
    __builtin_amdgcn_s_setprio(0);
    if (k0 + 32 < kend) {
      if (morestage) asm volatile("s_waitcnt vmcnt(4)" ::: "memory");  // k+1 landed
      else           asm volatile("s_waitcnt vmcnt(0)" ::: "memory");  // tail drain
      __builtin_amdgcn_s_barrier();
    }
    cur ^= 1;
  }

  if (SPLITK > 1) {
    float* P = (float*)Cv + (size_t)slice * TOK * N;
#pragma unroll
    for (int m = 0; m < 4; ++m)
#pragma unroll
      for (int n = 0; n < 4; ++n)
#pragma unroll
        for (int r = 0; r < 4; ++r) {
          const size_t idx = (size_t)(m0 + wr * 64 + m * 16 + g * 4 + r) * N
                           + n0 + wc * 64 + n * 16 + ln;
          P[idx] = acc[m][n][r];
        }
    return;
  }

  const float* bp = bias0;
  int nbase = n0;
  float scale = 1.f;
  if (QKV) {
    const int seg = n0 >> 10;
    bp = (seg == 0) ? bias0 : (seg == 1) ? bias1 : bias2;
    nbase = n0 & 1023;
    if (seg == 0) scale = 0.125f * 1.44269504f;  // 1/sqrt(64) * log2(e)
  }
  float bv[4];
#pragma unroll
  for (int n = 0; n < 4; ++n) bv[n] = bp[nbase + wc * 64 + n * 16 + ln];
#pragma unroll
  for (int m = 0; m < 4; ++m)
#pragma unroll
    for (int n = 0; n < 4; ++n)
#pragma unroll
      for (int r = 0; r < 4; ++r) {
        float v = (acc[m][n][r] + bv[n]) * scale;
        if (RELU) v = fmaxf(v, 0.f);
        const size_t idx = (size_t)(m0 + wr * 64 + m * 16 + g * 4 + r) * N
                         + n0 + wc * 64 + n * 16 + ln;
        if (OUT16) ((f16*)Cv)[idx] = (f16)v;
        else       ((float*)Cv)[idx] = v;
      }
}

// ---------------------------------------------------------------------------
// x (f32) -> f16 copy, one float4 per thread
__global__ __launch_bounds__(256, 4)
void cast_f16(const float* __restrict__ in, f16* __restrict__ out) {
  const size_t i = ((size_t)blockIdx.x * 256 + threadIdx.x) * 4;
  float4 f = *(const float4*)(in + i);
  f16x4 hh;
  hh[0] = (f16)f.x; hh[1] = (f16)f.y; hh[2] = (f16)f.z; hh[3] = (f16)f.w;
  *(f16x4*)(out + i) = hh;
}

// ---------------------------------------------------------------------------
// Flash attention, swapped-QK^T structure (unchanged from round 5 — verified)
template<int BASE>
__device__ __forceinline__ f16x8 pack_frag(f32x16 p) {
  f16x8 r;
#pragma unroll
  for (int j = 0; j < 8; ++j) r[j] = (f16)p[BASE + j];
  return r;
}

#define VSTRIDE 68   // f16 row stride of V^T (d-major)
#define NKT (SEQ / 64)

__global__ __launch_bounds__(256, 2)
void attention(const f16* __restrict__ qkv, f16* __restrict__ ctx) {
  __shared__ f16 Ks[2][64 * 64];
  __shared__ f16 VTs[2][64 * VSTRIDE];
  const int tid = threadIdx.x;
  const int l = tid & 63, w = tid >> 6;
  const int ln = l & 31, hi = l >> 5;
  const int bh = blockIdx.y, b = bh >> 4, h = bh & 15;
  const int q0 = blockIdx.x * 128;

  f16x8 qf[4];
  {
    const f16* qp = qkv + (size_t)(b * SEQ + q0 + w * 32 + ln) * 3072 + h * 64 + hi * 8;
#pragma unroll
    for (int kc = 0; kc < 4; ++kc) qf[kc] = *(const f16x8*)(qp + kc * 16);
  }

  f32x16 o0 = {}, o1 = {};
  float mrow = -1e30f, lrow = 0.f;

  const int skey = tid >> 3, sc = tid & 7;
  const f16* kbase = qkv + (size_t)(b * SEQ) * 3072 + 1024 + h * 64;
  const f16* vbase = qkv + (size_t)(b * SEQ) * 3072 + 2048 + h * 64;
  const int wbase = sc * 8 * VSTRIDE + (skey ^ (sc << 2));

  auto gloadK = [&](int buf, int kt) {
#pragma unroll
    for (int p = 0; p < 2; ++p) {
      const int key = p * 32 + skey;
      gload16(kbase + (size_t)(kt * 64 + key) * 3072 + 8 * (sc ^ (key & 7)),
              (void*)&Ks[buf][(p * 256 + w * 64) * 8]);
    }
  };
  auto scatterV = [&](int buf, f16x8 va, f16x8 vb2) {
#pragma unroll
    for (int j = 0; j < 8; ++j) {
      VTs[buf][wbase + VSTRIDE * j] = va[j];
      VTs[buf][wbase + VSTRIDE * j + 32] = vb2[j];
    }
  };

  {
    const f16* vp = vbase + (size_t)skey * 3072 + sc * 8;
    f16x8 va = *(const f16x8*)vp;
    f16x8 vb2 = *(const f16x8*)(vp + (size_t)32 * 3072);
    gloadK(0, 0);
    scatterV(0, va, vb2);
  }
  __syncthreads();

  const int sw0 = (ln >> 3) << 2;
  const int db0 = ln * VSTRIDE, db1 = (32 + ln) * VSTRIDE;

  auto body = [&](int kt, int cur) {
    const int nxt = cur ^ 1;
    f16x8 vna = {}, vnb = {};
    const bool more = (kt + 1 < NKT);
    if (more) {
      const f16* vp = vbase + (size_t)((kt + 1) * 64 + skey) * 3072 + sc * 8;
      vna = *(const f16x8*)vp;
      vnb = *(const f16x8*)(vp + (size_t)32 * 3072);
      gloadK(nxt, kt + 1);
    }
    f32x16 st0 = {}, st1 = {};
    __builtin_amdgcn_s_setprio(1);
#pragma unroll
    for (int kc = 0; kc < 4; ++kc) {
      const int m = kc * 2 + hi;
      const f16x8 kf0 = *(const f16x8*)&Ks[cur][(ln * 8 + (m ^ (ln & 7))) * 8];
      const f16x8 kf1 = *(const f16x8*)&Ks[cur][((32 + ln) * 8 + (m ^ (ln & 7))) * 8];
      st0 = __builtin_amdgcn_mfma_f32_32x32x16_f16(kf0, qf[kc], st0, 0, 0, 0);
      st1 = __builtin_amdgcn_mfma_f32_32x32x16_f16(kf1, qf[kc], st1, 0, 0, 0);
    }
    __builtin_amdgcn_s_setprio(0);

    float tm[16];
#pragma unroll
    for (int r = 0; r < 16; ++r) tm[r] = fmaxf(st0[r], st1[r]);
#pragma unroll
    for (int s2 = 8; s2 >= 1; s2 >>= 1)
#pragma unroll
      for (int r = 0; r < s2; ++r) tm[r] = fmaxf(tm[r], tm[r + s2]);
    const float mt = fmaxf(tm[0], __shfl_xor(tm[0], 32));
    if (!__all(mt <= mrow + 8.f)) {
      const float mn = fmaxf(mrow, mt);
      const float al = exp2f(mrow - mn);
      mrow = mn;
      lrow *= al;
#pragma unroll
      for (int r = 0; r < 16; ++r) { o0[r] *= al; o1[r] *= al; }
    }
    float ts[16];
#pragma unroll
    for (int r = 0; r < 16; ++r) {
      st0[r] = exp2f(st0[r] - mrow);
      st1[r] = exp2f(st1[r] - mrow);
      ts[r] = st0[r] + st1[r];
    }
#pragma unroll
    for (int s2 = 8; s2 >= 1; s2 >>= 1)
#pragma unroll
      for (int r = 0; r < s2; ++r) ts[r] += ts[r + s2];
    lrow += ts[0] + __shfl_xor(ts[0], 32);

    f16x8 pf[4];
    pf[0] = pack_frag<0>(st0); pf[1] = pack_frag<8>(st0);
    pf[2] = pack_frag<0>(st1); pf[3] = pack_frag<8>(st1);

    __builtin_amdgcn_s_setprio(1);
#pragma unroll
    for (int s = 0; s < 4; ++s) {
      const int k0 = 16 * s + 4 * hi;
      {
        const int p0 = k0 ^ sw0;
        f16x4 x = *(const f16x4*)&VTs[cur][db0 + p0];
        f16x4 y = *(const f16x4*)&VTs[cur][db0 + (p0 ^ 8)];
        f16x8 vf = __builtin_shufflevector(x, y, 0, 1, 2, 3, 4, 5, 6, 7);
        o0 = __builtin_amdgcn_mfma_f32_32x32x16_f16(vf, pf[s], o0, 0, 0, 0);
      }
      {
        const int p1 = k0 ^ sw0 ^ 16;
        f16x4 x = *(const f16x4*)&VTs[cur][db1 + p1];
        f16x4 y = *(const f16x4*)&VTs[cur][db1 + (p1 ^ 8)];
        f16x8 vf = __builtin_shufflevector(x, y, 0, 1, 2, 3, 4, 5, 6, 7);
        o1 = __builtin_amdgcn_mfma_f32_32x32x16_f16(vf, pf[s], o1, 0, 0, 0);
      }
    }
    __builtin_amdgcn_s_setprio(0);

    if (more) scatterV(nxt, vna, vnb);
    __syncthreads();
  };

#pragma unroll 1
  for (int kt = 0; kt < NKT; kt += 2) { body(kt, 0); body(kt + 1, 1); }

  const float inv = 1.f / lrow;
  f16* cp = ctx + (size_t)(b * SEQ + q0 + w * 32 + ln) * EMBED + h * 64;
#pragma unroll
  for (int r = 0; r < 16; ++r) {
    const int drow = (r & 3) + 8 * (r >> 2) + 4 * hi;
    cp[drow] = (f16)(o0[r] * inv);
    cp[32 + drow] = (f16)(o1[r] * inv);
  }
}

// ---------------------------------------------------------------------------
// out = LayerNorm(resid + bias + sum_p parts[p]) * g + be  (unchanged)
template<int NP, int OUT16>
__global__ __launch_bounds__(256, 4)
void add_ln(const float* parts, const float* __restrict__ bias,
            const float* resid, const float* __restrict__ gam,
            const float* __restrict__ bet, float* out, f16* __restrict__ out16) {
  const int t = blockIdx.x;
  const int tid = threadIdx.x;
  const size_t base = (size_t)t * EMBED + tid * 4;
  float4 rv = *(const float4*)(resid + base);
  float4 bb = *(const float4*)(bias + tid * 4);
  float x0 = rv.x + bb.x, x1 = rv.y + bb.y, x2 = rv.z + bb.z, x3 = rv.w + bb.w;
#pragma unroll
  for (int p = 0; p < NP; ++p) {
    float4 pv = *(const float4*)(parts + (size_t)p * TOK * EMBED + base);
    x0 += pv.x; x1 += pv.y; x2 += pv.z; x3 += pv.w;
  }
  float s1 = x0 + x1 + x2 + x3;
  float s2 = x0 * x0 + x1 * x1 + x2 * x2 + x3 * x3;
  for (int off = 1; off < 64; off <<= 1) {
    s1 += __shfl_xor(s1, off);
    s2 += __shfl_xor(s2, off);
  }
  __shared__ float red[8];
  if ((tid & 63) == 0) { red[(tid >> 6) * 2] = s1; red[(tid >> 6) * 2 + 1] = s2; }
  __syncthreads();
  s1 = red[0] + red[2] + red[4] + red[6];
  s2 = red[1] + red[3] + red[5] + red[7];
  const float mu = s1 * (1.f / EMBED);
  const float var = s2 * (1.f / EMBED) - mu * mu;
  const float rstd = rsqrtf(var + 1e-6f);
  float4 gv = *(const float4*)(gam + tid * 4);
  float4 bv = *(const float4*)(bet + tid * 4);
  float4 ov;
  ov.x = (x0 - mu) * rstd * gv.x + bv.x;
  ov.y = (x1 - mu) * rstd * gv.y + bv.y;
  ov.z = (x2 - mu) * rstd * gv.z + bv.z;
  ov.w = (x3 - mu) * rstd * gv.w + bv.w;
  *(float4*)(out + base) = ov;
  if (OUT16) {
    f16x4 hh;
    hh[0] = (f16)ov.x; hh[1] = (f16)ov.y; hh[2] = (f16)ov.z; hh[3] = (f16)ov.w;
    *(f16x4*)(out16 + base) = hh;
  }
}

// ---------------------------------------------------------------------------
// Wt[N][K] f16 = transpose(in[K][N] f32); 32x32 tiles  (unchanged)
__device__ __forceinline__ void transpose_tile(const float* in, f16* out,
                                               int K, int N, int k0, int n0, int tid) {
  __shared__ float t[32][33];
  {
    const int ky = tid >> 3, nx = (tid & 7) * 4;
    float4 f = *(const float4*)(in + (size_t)(k0 + ky) * N + n0 + nx);
    t[ky][nx] = f.x; t[ky][nx + 1] = f.y; t[ky][nx + 2] = f.z; t[ky][nx + 3] = f.w;
  }
  __syncthreads();
  const int ny = tid >> 3, kx = (tid & 7) * 4;
  f16x4 hh;
  hh[0] = (f16)t[kx][ny];     hh[1] = (f16)t[kx + 1][ny];
  hh[2] = (f16)t[kx + 2][ny]; hh[3] = (f16)t[kx + 3][ny];
  *(f16x4*)(out + (size_t)(n0 + ny) * K + k0 + kx) = hh;
}

__global__ __launch_bounds__(256, 4)
void transpose_w(const float* __restrict__ in, f16* __restrict__ out,
                 int K, int N) {
  transpose_tile(in, out, K, N, blockIdx.y * 32, blockIdx.x * 32, threadIdx.x);
}

__global__ __launch_bounds__(256, 4)
void transpose_qkv(const float* __restrict__ w0, const float* __restrict__ w1,
                   const float* __restrict__ w2, f16* __restrict__ out) {
  const float* in = (blockIdx.z == 0) ? w0 : (blockIdx.z == 1) ? w1 : w2;
  f16* o = out + (size_t)blockIdx.z * 1024 * 1024;
  transpose_tile(in, o, 1024, 1024, blockIdx.y * 32, blockIdx.x * 32, threadIdx.x);
}

// ---------------------------------------------------------------------------
extern "C" void kernel_launch(void* const* d_in, const int* in_sizes, int n_in,
                              void* d_out, int out_size, void* d_ws, size_t ws_size,
                              hipStream_t stream) {
  const float* x    = (const float*)d_in[0];
  const float* Wq   = (const float*)d_in[1];
  const float* bq   = (const float*)d_in[2];
  const float* Wk   = (const float*)d_in[3];
  const float* bk   = (const float*)d_in[4];
  const float* Wv   = (const float*)d_in[5];
  const float* bv   = (const float*)d_in[6];
  const float* Wo   = (const float*)d_in[7];
  const float* bo   = (const float*)d_in[8];
  const float* ln1g = (const float*)d_in[9];
  const float* ln1b = (const float*)d_in[10];
  const float* W1   = (const float*)d_in[11];
  const float* b1   = (const float*)d_in[12];
  const float* W2   = (const float*)d_in[13];
  const float* b2   = (const float*)d_in[14];
  const float* ln2g = (const float*)d_in[15];
  const float* ln2b = (const float*)d_in[16];
  float* out = (float*)d_out;

  // workspace (96 MB):
  //  0: WtQKV f16 6MB | 6: WtO 2MB | 8: Wt1 8MB | 16: Wt2 8MB
  // 24: qkv f16 24MB (later hid f16 32MB over 24-56) | 48: ctx f16 8MB
  //     (x16 f16 8MB lives at 48 before attention overwrites it with ctx)
  // 56: parts f32 2x16MB | 88: x1h f16 8MB.  x1 (f32) lives in d_out.
  char* ws = (char*)d_ws;
  const size_t MB = 1024 * 1024;
  f16*   WtQKV = (f16*)(ws);
  f16*   WtO   = (f16*)(ws + 6 * MB);
  f16*   Wt1   = (f16*)(ws + 8 * MB);
  f16*   Wt2   = (f16*)(ws + 16 * MB);
  f16*   qkv   = (f16*)(ws + 24 * MB);
  f16*   ctx   = (f16*)(ws + 48 * MB);
  f16*   x16   = (f16*)(ws + 48 * MB);   // dead once qkv is built
  float* parts = (float*)(ws + 56 * MB);
  f16*   x1h   = (f16*)(ws + 88 * MB);
  f16*   hid   = (f16*)(ws + 24 * MB);
  float* x1    = out;   // d_out doubles as x1 storage

  const dim3 blk(256);
  transpose_qkv<<<dim3(32, 32, 3), blk, 0, stream>>>(Wq, Wk, Wv, WtQKV);
  transpose_w<<<dim3(32, 32), blk, 0, stream>>>(Wo, WtO, 1024, 1024);
  transpose_w<<<dim3(128, 32), blk, 0, stream>>>(W1, Wt1, 1024, 4096);
  transpose_w<<<dim3(32, 128), blk, 0, stream>>>(W2, Wt2, 4096, 1024);
  cast_f16<<<4096, blk, 0, stream>>>(x, x16);

  gemm_f16<0, 1, 1, 1><<<768, blk, 0, stream>>>(x16, WtQKV, bq, bk, bv, qkv, 3072, 1024, 24);
  attention<<<dim3(16, 32), blk, 0, stream>>>(qkv, ctx);
  gemm_f16<0, 0, 0, 2><<<512, blk, 0, stream>>>(ctx, WtO, nullptr, nullptr, nullptr, parts, 1024, 1024, 8);
  add_ln<2, 1><<<4096, blk, 0, stream>>>(parts, bo, x, ln1g, ln1b, x1, x1h);
  gemm_f16<1, 1, 0, 1><<<1024, blk, 0, stream>>>(x1h, Wt1, b1, nullptr, nullptr, hid, 4096, 1024, 32);
  gemm_f16<0, 0, 0, 2><<<512, blk, 0, stream>>>(hid, Wt2, nullptr, nullptr, nullptr, parts, 1024, 4096, 8);
  add_ln<2, 0><<<4096, blk, 0, stream>>>(parts, b2, x1, ln2g, ln2b, out, nullptr);
}